// Round 9
// baseline (216.548 us; speedup 1.0000x reference)
//
#include <hip/hip_runtime.h>

#define N_NODES 100000
#define N_EDGES 1600000

typedef __attribute__((ext_vector_type(8))) short short8;
typedef __attribute__((ext_vector_type(4))) float f32x4;
typedef __attribute__((ext_vector_type(2))) unsigned short ushort2v;
typedef __attribute__((ext_vector_type(4))) unsigned short ushort4v;
typedef __attribute__((ext_vector_type(8))) unsigned short ushort8v;

static __device__ inline unsigned short f2bf(float f) {
    union { float f; unsigned u; } v; v.f = f;
    unsigned r = v.u + 0x7FFF + ((v.u >> 16) & 1);   // round-to-nearest-even
    return (unsigned short)(r >> 16);
}
static __device__ inline float bf2f(unsigned short u) {
    union { unsigned u; float f; } v; v.u = ((unsigned)u) << 16;
    return v.f;
}

// ---------------- row_ptr via binary search over sorted dst ----------------
__global__ __launch_bounds__(256) void rowptr_k(const int* __restrict__ dst,
                                                int* __restrict__ rp) {
    int t = blockIdx.x * blockDim.x + threadIdx.x;
    if (t > N_NODES) return;
    int lo = 0, hi = N_EDGES;
    while (lo < hi) {
        int mid = (lo + hi) >> 1;
        if (dst[mid] < t) lo = mid + 1; else hi = mid;
    }
    rp[t] = lo;
}

// ---------------- weight prep: transpose + bf16 ----------------------------
__global__ __launch_bounds__(256) void prep_k(const float* __restrict__ w1,
                                              const float* __restrict__ w2,
                                              const float* __restrict__ l0w,
                                              unsigned short* __restrict__ w1t,
                                              unsigned short* __restrict__ w2t,
                                              unsigned short* __restrict__ w0t) {
    int id = blockIdx.x * blockDim.x + threadIdx.x;
    if (id < 128 * 160) {
        int o = id / 160, k = id - o * 160;
        w1t[id] = (k < 144) ? f2bf(w1[k * 128 + o]) : (unsigned short)0;
    } else if (id < 128 * 160 + 64 * 128) {
        int j = id - 128 * 160;
        int o = j / 128, k = j - o * 128;
        w2t[j] = f2bf(w2[k * 64 + o]);
    } else if (id < 128 * 160 + 64 * 128 + 80 * 64) {
        int j = id - 128 * 160 - 64 * 128;
        int o = j / 64, k = j - o * 64;
        w0t[j] = (o < 72 && k < 36) ? f2bf(l0w[k * 72 + o]) : (unsigned short)0;
    }
}

// ---------------- x -> bf16 [N][4] (pad col3 = 0) --------------------------
__global__ __launch_bounds__(256) void x2b_k(const float* __restrict__ x,
                                             unsigned short* __restrict__ xb4) {
    int t = blockIdx.x * blockDim.x + threadIdx.x;
    if (t >= N_NODES) return;
    ushort4v w;
    w[0] = f2bf(x[(size_t)t * 3 + 0]);
    w[1] = f2bf(x[(size_t)t * 3 + 1]);
    w[2] = f2bf(x[(size_t)t * 3 + 2]);
    w[3] = 0;
    *reinterpret_cast<ushort4v*>(xb4 + (size_t)t * 4) = w;
}

// ---------------- conv1 per-node: gather xb4 (1 x 8B req/edge) -------------
__global__ __launch_bounds__(256) void conv1n_k(const unsigned short* __restrict__ xb4,
                                                const float* __restrict__ kv,
                                                const int* __restrict__ src,
                                                const int* __restrict__ rp,
                                                unsigned short* __restrict__ hcb) {
    int t = blockIdx.x * blockDim.x + threadIdx.x;
    if (t >= N_NODES) return;
    int e0 = rp[t], e1 = rp[t + 1];
    float a0[3] = {0.f, 0.f, 0.f}, a1[3] = {0.f, 0.f, 0.f};
    int e = e0;
    for (; e + 8 <= e1; e += 8) {
        int s[8]; float k0[8], k1[8];
#pragma unroll
        for (int u = 0; u < 8; ++u) s[u]  = src[e + u];
#pragma unroll
        for (int u = 0; u < 8; ++u) k0[u] = kv[e + u];
#pragma unroll
        for (int u = 0; u < 8; ++u) k1[u] = kv[N_EDGES + e + u];
        ushort4v v[8];
#pragma unroll
        for (int u = 0; u < 8; ++u)
            v[u] = *reinterpret_cast<const ushort4v*>(xb4 + (size_t)s[u] * 4);
#pragma unroll
        for (int u = 0; u < 8; ++u) {
#pragma unroll
            for (int q = 0; q < 3; ++q) {
                float x = bf2f(v[u][q]);
                a0[q] += k0[u] * x;
                a1[q] += k1[u] * x;
            }
        }
    }
    for (; e < e1; ++e) {
        int s = src[e];
        float k0 = kv[e], k1 = kv[N_EDGES + e];
        ushort4v v = *reinterpret_cast<const ushort4v*>(xb4 + (size_t)s * 4);
#pragma unroll
        for (int q = 0; q < 3; ++q) {
            float x = bf2f(v[q]);
            a0[q] += k0 * x;
            a1[q] += k1 * x;
        }
    }
    ushort4v r0; ushort2v r1;
    r0[0] = f2bf(a0[0]); r0[1] = f2bf(a0[1]); r0[2] = f2bf(a0[2]); r0[3] = f2bf(a1[0]);
    r1[0] = f2bf(a1[1]); r1[1] = f2bf(a1[2]);
    *reinterpret_cast<ushort4v*>(hcb + (size_t)t * 20)     = r0;
    *reinterpret_cast<ushort2v*>(hcb + (size_t)t * 20 + 4) = r1;
}

// ---------------- conv2 per-node: gather hcb cols 0..5 (2 req/edge) --------
__global__ __launch_bounds__(256) void conv2n_k(const unsigned short* __restrict__ hcbr,
                                                const float* __restrict__ kv,
                                                const int* __restrict__ src,
                                                const int* __restrict__ rp,
                                                unsigned short* __restrict__ hcbw) {
    int t = blockIdx.x * blockDim.x + threadIdx.x;
    if (t >= N_NODES) return;
    int e0 = rp[t], e1 = rp[t + 1];
    float a0[6], a1[6];
#pragma unroll
    for (int q = 0; q < 6; ++q) { a0[q] = 0.f; a1[q] = 0.f; }
    int e = e0;
    for (; e + 8 <= e1; e += 8) {
        int s[8]; float k0[8], k1[8];
#pragma unroll
        for (int u = 0; u < 8; ++u) s[u]  = src[e + u];
#pragma unroll
        for (int u = 0; u < 8; ++u) k0[u] = kv[e + u];
#pragma unroll
        for (int u = 0; u < 8; ++u) k1[u] = kv[N_EDGES + e + u];
        ushort4v va[8]; ushort2v vb[8];
#pragma unroll
        for (int u = 0; u < 8; ++u) {
            const unsigned short* b = hcbr + (size_t)s[u] * 20;
            va[u] = *reinterpret_cast<const ushort4v*>(b);
            vb[u] = *reinterpret_cast<const ushort2v*>(b + 4);
        }
#pragma unroll
        for (int u = 0; u < 8; ++u) {
#pragma unroll
            for (int q = 0; q < 4; ++q) {
                float x = bf2f(va[u][q]);
                a0[q] += k0[u] * x;
                a1[q] += k1[u] * x;
            }
#pragma unroll
            for (int q = 0; q < 2; ++q) {
                float x = bf2f(vb[u][q]);
                a0[4 + q] += k0[u] * x;
                a1[4 + q] += k1[u] * x;
            }
        }
    }
    for (; e < e1; ++e) {
        int s = src[e];
        float k0 = kv[e], k1 = kv[N_EDGES + e];
        const unsigned short* b = hcbr + (size_t)s * 20;
        ushort4v va = *reinterpret_cast<const ushort4v*>(b);
        ushort2v vb = *reinterpret_cast<const ushort2v*>(b + 4);
#pragma unroll
        for (int q = 0; q < 4; ++q) {
            float x = bf2f(va[q]);
            a0[q] += k0 * x; a1[q] += k1 * x;
        }
#pragma unroll
        for (int q = 0; q < 2; ++q) {
            float x = bf2f(vb[q]);
            a0[4 + q] += k0 * x; a1[4 + q] += k1 * x;
        }
    }
    // write cols 6..17: a0 -> 6..11, a1 -> 12..17 (4B stores, all aligned)
    unsigned short* o = hcbw + (size_t)t * 20;
#pragma unroll
    for (int p = 0; p < 3; ++p) {
        ushort2v w0; w0[0] = f2bf(a0[p * 2]); w0[1] = f2bf(a0[p * 2 + 1]);
        *reinterpret_cast<ushort2v*>(o + 6 + p * 2) = w0;
        ushort2v w1; w1[0] = f2bf(a1[p * 2]); w1[1] = f2bf(a1[p * 2 + 1]);
        *reinterpret_cast<ushort2v*>(o + 12 + p * 2) = w1;
    }
}

// ---------------- conv3 per-node: gather hcb cols 0..17 (3 req/edge) -------
__global__ __launch_bounds__(256) void conv3n_k(const unsigned short* __restrict__ hcb,
                                                const float* __restrict__ kv,
                                                const int* __restrict__ src,
                                                const int* __restrict__ rp,
                                                unsigned short* __restrict__ h3b) {
    int t = blockIdx.x * blockDim.x + threadIdx.x;
    if (t >= N_NODES) return;
    int e0 = rp[t], e1 = rp[t + 1];
    float a0[18], a1[18];
#pragma unroll
    for (int q = 0; q < 18; ++q) { a0[q] = 0.f; a1[q] = 0.f; }
    int e = e0;
    for (; e + 4 <= e1; e += 4) {
        int s[4]; float k0[4], k1[4];
#pragma unroll
        for (int u = 0; u < 4; ++u) s[u]  = src[e + u];
#pragma unroll
        for (int u = 0; u < 4; ++u) k0[u] = kv[e + u];
#pragma unroll
        for (int u = 0; u < 4; ++u) k1[u] = kv[N_EDGES + e + u];
        ushort8v p0[4], p1[4]; ushort2v p2[4];
#pragma unroll
        for (int u = 0; u < 4; ++u) {
            const unsigned short* b = hcb + (size_t)s[u] * 20;
            p0[u] = *reinterpret_cast<const ushort8v*>(b);
            p1[u] = *reinterpret_cast<const ushort8v*>(b + 8);
            p2[u] = *reinterpret_cast<const ushort2v*>(b + 16);
        }
#pragma unroll
        for (int u = 0; u < 4; ++u) {
#pragma unroll
            for (int q = 0; q < 8; ++q) {
                float x = bf2f(p0[u][q]);
                a0[q] += k0[u] * x; a1[q] += k1[u] * x;
            }
#pragma unroll
            for (int q = 0; q < 8; ++q) {
                float x = bf2f(p1[u][q]);
                a0[8 + q] += k0[u] * x; a1[8 + q] += k1[u] * x;
            }
#pragma unroll
            for (int q = 0; q < 2; ++q) {
                float x = bf2f(p2[u][q]);
                a0[16 + q] += k0[u] * x; a1[16 + q] += k1[u] * x;
            }
        }
    }
    for (; e < e1; ++e) {
        int s = src[e];
        float k0 = kv[e], k1 = kv[N_EDGES + e];
        const unsigned short* b = hcb + (size_t)s * 20;
        ushort8v p0 = *reinterpret_cast<const ushort8v*>(b);
        ushort8v p1 = *reinterpret_cast<const ushort8v*>(b + 8);
        ushort2v p2 = *reinterpret_cast<const ushort2v*>(b + 16);
#pragma unroll
        for (int q = 0; q < 8; ++q) {
            float x = bf2f(p0[q]); a0[q] += k0 * x; a1[q] += k1 * x;
        }
#pragma unroll
        for (int q = 0; q < 8; ++q) {
            float x = bf2f(p1[q]); a0[8 + q] += k0 * x; a1[8 + q] += k1 * x;
        }
#pragma unroll
        for (int q = 0; q < 2; ++q) {
            float x = bf2f(p2[q]); a0[16 + q] += k0 * x; a1[16 + q] += k1 * x;
        }
    }
    // write h3b row: cols 0..17 = a0, 18..35 = a1, 36..63 = 0
    unsigned short* o = h3b + (size_t)t * 64;
    unsigned short r[36];
#pragma unroll
    for (int q = 0; q < 18; ++q) r[q] = f2bf(a0[q]);
#pragma unroll
    for (int q = 0; q < 18; ++q) r[18 + q] = f2bf(a1[q]);
#pragma unroll
    for (int p = 0; p < 4; ++p) {
        ushort8v w;
#pragma unroll
        for (int q = 0; q < 8; ++q) w[q] = r[p * 8 + q];
        *reinterpret_cast<ushort8v*>(o + p * 8) = w;
    }
    {
        ushort4v w;
#pragma unroll
        for (int q = 0; q < 4; ++q) w[q] = r[32 + q];
        *reinterpret_cast<ushort4v*>(o + 32) = w;
    }
    ushort4v z = {0, 0, 0, 0};
#pragma unroll
    for (int j = 36; j < 64; j += 4)
        *reinterpret_cast<ushort4v*>(o + j) = z;
}

template<int VEC> struct VecU;
template<> struct VecU<4> { using T = ushort4v; };
template<> struct VecU<8> { using T = ushort8v; };

// ---------------- bf16 aniso conv (conv4) ----------------------------------
template<int C, int VEC, int IN_STRIDE, int OUT_STRIDE, int OUT_OFF,
         int PAD_FROM, int PAD_TO>
__global__ __launch_bounds__(256) void convb_k(const unsigned short* __restrict__ hin,
                                               const float* __restrict__ kv,
                                               const int* __restrict__ src,
                                               const int* __restrict__ rp,
                                               unsigned short* __restrict__ hout) {
    constexpr int G = C / VEC;
    using VT = typename VecU<VEC>::T;
    int id = blockIdx.x * blockDim.x + threadIdx.x;
    if (id >= N_NODES * G) return;
    int t = id / G;
    int g = id - t * G;
    int c0 = g * VEC;
    int e0 = rp[t], e1 = rp[t + 1];

    float a0[VEC], a1[VEC];
#pragma unroll
    for (int q = 0; q < VEC; ++q) { a0[q] = 0.f; a1[q] = 0.f; }

    int e = e0;
    for (; e + 8 <= e1; e += 8) {
        int s[8]; float k0[8], k1[8];
#pragma unroll
        for (int u = 0; u < 8; ++u) s[u]  = src[e + u];
#pragma unroll
        for (int u = 0; u < 8; ++u) k0[u] = kv[e + u];
#pragma unroll
        for (int u = 0; u < 8; ++u) k1[u] = kv[N_EDGES + e + u];
        VT v[8];
#pragma unroll
        for (int u = 0; u < 8; ++u)
            v[u] = *reinterpret_cast<const VT*>(hin + (size_t)s[u] * IN_STRIDE + c0);
#pragma unroll
        for (int u = 0; u < 8; ++u) {
#pragma unroll
            for (int q = 0; q < VEC; ++q) {
                float x = bf2f(v[u][q]);
                a0[q] += k0[u] * x;
                a1[q] += k1[u] * x;
            }
        }
    }
    for (; e < e1; ++e) {
        int s = src[e];
        float k0 = kv[e], k1 = kv[N_EDGES + e];
        VT v = *reinterpret_cast<const VT*>(hin + (size_t)s * IN_STRIDE + c0);
#pragma unroll
        for (int q = 0; q < VEC; ++q) {
            float x = bf2f(v[q]);
            a0[q] += k0 * x;
            a1[q] += k1 * x;
        }
    }

    VT r0, r1;
#pragma unroll
    for (int q = 0; q < VEC; ++q) { r0[q] = f2bf(a0[q]); r1[q] = f2bf(a1[q]); }
    *reinterpret_cast<VT*>(hout + (size_t)t * OUT_STRIDE + OUT_OFF + c0)     = r0;
    *reinterpret_cast<VT*>(hout + (size_t)t * OUT_STRIDE + OUT_OFF + C + c0) = r1;

    if constexpr (PAD_TO > PAD_FROM) {
        if (g == G - 1) {
            ushort4v z = {0, 0, 0, 0};
#pragma unroll
            for (int j = PAD_FROM; j < PAD_TO; j += 4)
                *reinterpret_cast<ushort4v*>(hout + (size_t)t * OUT_STRIDE + j) = z;
        }
    }
}

// ---------------- lin0 via MFMA: h4b = relu(h3b[N][64] @ w0t + b0) ---------
__global__ __launch_bounds__(256) void lin0m_k(const unsigned short* __restrict__ h3b,
                                               const unsigned short* __restrict__ w0t,
                                               const float* __restrict__ b0,
                                               unsigned short* __restrict__ h4b) {
    int tid = threadIdx.x;
    int w = tid >> 6;
    int lane = tid & 63;
    int lr = lane & 15;
    int kg = lane >> 4;
    int row_base = blockIdx.x * 64 + w * 16;

    f32x4 acc[5];
#pragma unroll
    for (int n = 0; n < 5; ++n) acc[n] = (f32x4){0.f, 0.f, 0.f, 0.f};

    const unsigned short* arow = h3b + (size_t)(row_base + lr) * 64 + kg * 8;
#pragma unroll
    for (int ks = 0; ks < 2; ++ks) {
        short8 a = *reinterpret_cast<const short8*>(arow + ks * 32);
#pragma unroll
        for (int n = 0; n < 5; ++n) {
            short8 b = *reinterpret_cast<const short8*>(w0t + (n * 16 + lr) * 64 + ks * 32 + kg * 8);
            acc[n] = __builtin_amdgcn_mfma_f32_16x16x32_bf16(a, b, acc[n], 0, 0, 0);
        }
    }
#pragma unroll
    for (int n = 0; n < 5; ++n) {
        int col = n * 16 + lr;
        if (col < 72) {
            float bv = b0[col];
#pragma unroll
            for (int q = 0; q < 4; ++q) {
                int t = row_base + kg * 4 + q;
                if (t < N_NODES)
                    h4b[(size_t)t * 72 + col] = f2bf(fmaxf(acc[n][q] + bv, 0.f));
            }
        }
    }
}

// ---------------- MFMA MLP head + L2 normalize -----------------------------
#define HSTRIDE 136
__global__ __launch_bounds__(256) void mlp_k(const unsigned short* __restrict__ h5b,
                                             const unsigned short* __restrict__ w1t,
                                             const float* __restrict__ b1,
                                             const unsigned short* __restrict__ w2t,
                                             const float* __restrict__ b2,
                                             float* __restrict__ out) {
    __shared__ unsigned short sh[64 * HSTRIDE];
    int tid = threadIdx.x;
    int w = tid >> 6;
    int lane = tid & 63;
    int lr = lane & 15;
    int kg = lane >> 4;
    int row_base = blockIdx.x * 64 + w * 16;

    f32x4 acc[8];
#pragma unroll
    for (int n = 0; n < 8; ++n) acc[n] = (f32x4){0.f, 0.f, 0.f, 0.f};

    const unsigned short* arow = h5b + (size_t)(row_base + lr) * 160 + kg * 8;
#pragma unroll
    for (int ks = 0; ks < 5; ++ks) {
        short8 a = *reinterpret_cast<const short8*>(arow + ks * 32);
#pragma unroll
        for (int n = 0; n < 8; ++n) {
            short8 b = *reinterpret_cast<const short8*>(w1t + (n * 16 + lr) * 160 + ks * 32 + kg * 8);
            acc[n] = __builtin_amdgcn_mfma_f32_16x16x32_bf16(a, b, acc[n], 0, 0, 0);
        }
    }
#pragma unroll
    for (int n = 0; n < 8; ++n) {
        float bv = b1[n * 16 + lr];
#pragma unroll
        for (int q = 0; q < 4; ++q) {
            float hv = fmaxf(acc[n][q] + bv, 0.f);
            sh[(w * 16 + kg * 4 + q) * HSTRIDE + n * 16 + lr] = f2bf(hv);
        }
    }
    __syncthreads();

    f32x4 acc2[4];
#pragma unroll
    for (int n = 0; n < 4; ++n) acc2[n] = (f32x4){0.f, 0.f, 0.f, 0.f};
#pragma unroll
    for (int ks = 0; ks < 4; ++ks) {
        short8 a = *reinterpret_cast<const short8*>(sh + (w * 16 + lr) * HSTRIDE + ks * 32 + kg * 8);
#pragma unroll
        for (int n = 0; n < 4; ++n) {
            short8 b = *reinterpret_cast<const short8*>(w2t + (n * 16 + lr) * 128 + ks * 32 + kg * 8);
            acc2[n] = __builtin_amdgcn_mfma_f32_16x16x32_bf16(a, b, acc2[n], 0, 0, 0);
        }
    }

    float v[4][4];
    float ss[4];
#pragma unroll
    for (int q = 0; q < 4; ++q) ss[q] = 0.f;
#pragma unroll
    for (int n = 0; n < 4; ++n) {
        float bv = b2[n * 16 + lr];
#pragma unroll
        for (int q = 0; q < 4; ++q) {
            float x = acc2[n][q] + bv;
            v[n][q] = x;
            ss[q] += x * x;
        }
    }
#pragma unroll
    for (int q = 0; q < 4; ++q) {
#pragma unroll
        for (int d = 1; d < 16; d <<= 1) ss[q] += __shfl_xor(ss[q], d);
    }
#pragma unroll
    for (int q = 0; q < 4; ++q) {
        int node = row_base + kg * 4 + q;
        if (node < N_NODES) {
            float scale = 1.f / fmaxf(sqrtf(ss[q]), 1e-12f);
#pragma unroll
            for (int n = 0; n < 4; ++n)
                out[(size_t)node * 64 + n * 16 + lr] = v[n][q] * scale;
        }
    }
}

extern "C" void kernel_launch(void* const* d_in, const int* in_sizes, int n_in,
                              void* d_out, int out_size, void* d_ws, size_t ws_size,
                              hipStream_t stream) {
    const float* x   = (const float*)d_in[0];
    const float* kdd = (const float*)d_in[1];
    const float* kda = (const float*)d_in[2];
    const float* l0w = (const float*)d_in[3];
    const float* l0b = (const float*)d_in[4];
    const float* w1  = (const float*)d_in[5];
    const float* b1  = (const float*)d_in[6];
    const float* w2  = (const float*)d_in[7];
    const float* b2  = (const float*)d_in[8];
    const int*   src = (const int*)d_in[9];
    const int*   dst = (const int*)d_in[10];
    float* out = (float*)d_out;
    char* ws = (char*)d_ws;

    // workspace layout (bytes):
    //   rp    [0, +400004)
    //   w0t   [400384, +10240)        bf16 80x64
    //   w1t   [410624, +40960)        bf16 128x160
    //   w2t   [451584, +16384)        bf16 64x128
    //   hcb   [475136, +4.0 MB)       bf16 N*20
    //   h3b   [4480000, +12.80 MB)    bf16 100032*64 (K-padded)
    //   h4b   [17284096, +14.4 MB)    bf16 N*72
    //   h5b   [31684096, +32.01 MB)   bf16 100032*160
    //   xb4   [31684096, +800 KB)     bf16 N*4 — overlays h5b head; dead
    //                                 before conv4 writes h5b.
    int*   rp  = (int*)ws;
    unsigned short* w0t = (unsigned short*)(ws + 400384u);
    unsigned short* w1t = (unsigned short*)(ws + 410624u);
    unsigned short* w2t = (unsigned short*)(ws + 451584u);
    unsigned short* hcb = (unsigned short*)(ws + 475136u);
    unsigned short* h3b = (unsigned short*)(ws + 4480000u);
    unsigned short* h4b = (unsigned short*)(ws + 17284096u);
    unsigned short* h5b = (unsigned short*)(ws + 31684096u);
    unsigned short* xb4 = (unsigned short*)(ws + 31684096u);

    int nb = (N_NODES + 255) / 256;
    rowptr_k<<<(N_NODES + 1 + 255) / 256, 256, 0, stream>>>(dst, rp);
    prep_k<<<(128 * 160 + 64 * 128 + 80 * 64 + 255) / 256, 256, 0, stream>>>(w1, w2, l0w, w1t, w2t, w0t);
    x2b_k<<<nb, 256, 0, stream>>>(x, xb4);

    // DD phase: xb4 -> h1 (hcb cols 0:6) -> h2 (hcb cols 6:18)
    conv1n_k<<<nb, 256, 0, stream>>>(xb4, kdd, src, rp, hcb);
    conv2n_k<<<nb, 256, 0, stream>>>(hcb, kdd, src, rp, hcb);

    // DA phase
    conv3n_k<<<nb, 256, 0, stream>>>(hcb, kda, src, rp, h3b);
    lin0m_k<<<(N_NODES + 63) / 64, 256, 0, stream>>>(h3b, w0t, l0b, h4b);
    convb_k<72, 8, 72, 160, 0, 144, 160><<<(N_NODES * 9 + 255) / 256, 256, 0, stream>>>(h4b, kda, src, rp, h5b);

    // MFMA MLP head + normalize
    mlp_k<<<(N_NODES + 63) / 64, 256, 0, stream>>>(h5b, w1t, b1, w2t, b2, out);
}

// Round 10
// 207.424 us; speedup vs baseline: 1.0440x; 1.0440x over previous
//
#include <hip/hip_runtime.h>

#define N_NODES 100000
#define N_EDGES 1600000

typedef __attribute__((ext_vector_type(8))) short short8;
typedef __attribute__((ext_vector_type(4))) float f32x4;
typedef __attribute__((ext_vector_type(2))) unsigned short ushort2v;
typedef __attribute__((ext_vector_type(4))) unsigned short ushort4v;
typedef __attribute__((ext_vector_type(8))) unsigned short ushort8v;

static __device__ inline unsigned short f2bf(float f) {
    union { float f; unsigned u; } v; v.f = f;
    unsigned r = v.u + 0x7FFF + ((v.u >> 16) & 1);   // round-to-nearest-even
    return (unsigned short)(r >> 16);
}
static __device__ inline float bf2f(unsigned short u) {
    union { unsigned u; float f; } v; v.u = ((unsigned)u) << 16;
    return v.f;
}

// ---------------- row_ptr via binary search over sorted dst ----------------
__global__ __launch_bounds__(256) void rowptr_k(const int* __restrict__ dst,
                                                int* __restrict__ rp) {
    int t = blockIdx.x * blockDim.x + threadIdx.x;
    if (t > N_NODES) return;
    int lo = 0, hi = N_EDGES;
    while (lo < hi) {
        int mid = (lo + hi) >> 1;
        if (dst[mid] < t) lo = mid + 1; else hi = mid;
    }
    rp[t] = lo;
}

// ---------------- weight prep: transpose + bf16 ----------------------------
__global__ __launch_bounds__(256) void prep_k(const float* __restrict__ w1,
                                              const float* __restrict__ w2,
                                              const float* __restrict__ l0w,
                                              unsigned short* __restrict__ w1t,
                                              unsigned short* __restrict__ w2t,
                                              unsigned short* __restrict__ w0t) {
    int id = blockIdx.x * blockDim.x + threadIdx.x;
    if (id < 128 * 160) {
        int o = id / 160, k = id - o * 160;
        w1t[id] = (k < 144) ? f2bf(w1[k * 128 + o]) : (unsigned short)0;
    } else if (id < 128 * 160 + 64 * 128) {
        int j = id - 128 * 160;
        int o = j / 128, k = j - o * 128;
        w2t[j] = f2bf(w2[k * 64 + o]);
    } else if (id < 128 * 160 + 64 * 128 + 80 * 64) {
        int j = id - 128 * 160 - 64 * 128;
        int o = j / 64, k = j - o * 64;
        w0t[j] = (o < 72 && k < 36) ? f2bf(l0w[k * 72 + o]) : (unsigned short)0;
    }
}

// ---------------- conv1: per (t,c), gather x f32 (L2-hot) ------------------
__global__ __launch_bounds__(256) void conv1_k(const float* __restrict__ x,
                                               const float* __restrict__ kv,
                                               const int* __restrict__ src,
                                               const int* __restrict__ rp,
                                               unsigned short* __restrict__ hcb) {
    int id = blockIdx.x * blockDim.x + threadIdx.x;
    if (id >= N_NODES * 3) return;
    int t = id / 3;
    int c = id - t * 3;
    int e0 = rp[t], e1 = rp[t + 1];
    float a0 = 0.f, a1 = 0.f;
    int e = e0;
    for (; e + 8 <= e1; e += 8) {
        int s[8]; float k0[8], k1[8], v[8];
#pragma unroll
        for (int u = 0; u < 8; ++u) s[u]  = src[e + u];
#pragma unroll
        for (int u = 0; u < 8; ++u) k0[u] = kv[e + u];
#pragma unroll
        for (int u = 0; u < 8; ++u) k1[u] = kv[N_EDGES + e + u];
#pragma unroll
        for (int u = 0; u < 8; ++u) v[u]  = x[(size_t)s[u] * 3 + c];
#pragma unroll
        for (int u = 0; u < 8; ++u) { a0 += k0[u] * v[u]; a1 += k1[u] * v[u]; }
    }
    for (; e < e1; ++e) {
        int s = src[e];
        float v = x[(size_t)s * 3 + c];
        a0 += kv[e] * v;
        a1 += kv[N_EDGES + e] * v;
    }
    hcb[(size_t)t * 20 + c]     = f2bf(a0);
    hcb[(size_t)t * 20 + 3 + c] = f2bf(a1);
}

// ---------------- fused conv2 + conv3a: one h1 gather, 4 kernel weights ----
// Thread (t,g), g<3, h1 channels c0=2g..c0+1. Produces:
//   h2[t][6+c0..], h2[t][12+c0..]   (kdd)      -> hcb cols 6:18
//   h3[t][c0..],   h3[t][18+c0..]   (kda)      -> h3b
__global__ __launch_bounds__(256) void f23a_k(const unsigned short* __restrict__ hcbr,
                                              const float* __restrict__ kdd,
                                              const float* __restrict__ kda,
                                              const int* __restrict__ src,
                                              const int* __restrict__ rp,
                                              unsigned short* __restrict__ hcbw,
                                              unsigned short* __restrict__ h3b) {
    int id = blockIdx.x * blockDim.x + threadIdx.x;
    if (id >= N_NODES * 3) return;
    int t = id / 3;
    int g = id - t * 3;
    int c0 = g * 2;
    int e0 = rp[t], e1 = rp[t + 1];

    float dd0[2] = {0.f, 0.f}, dd1[2] = {0.f, 0.f};
    float da0[2] = {0.f, 0.f}, da1[2] = {0.f, 0.f};

    int e = e0;
    for (; e + 8 <= e1; e += 8) {
        int s[8]; float d0[8], d1[8], a0w[8], a1w[8];
#pragma unroll
        for (int u = 0; u < 8; ++u) s[u]   = src[e + u];
#pragma unroll
        for (int u = 0; u < 8; ++u) d0[u]  = kdd[e + u];
#pragma unroll
        for (int u = 0; u < 8; ++u) d1[u]  = kdd[N_EDGES + e + u];
#pragma unroll
        for (int u = 0; u < 8; ++u) a0w[u] = kda[e + u];
#pragma unroll
        for (int u = 0; u < 8; ++u) a1w[u] = kda[N_EDGES + e + u];
        ushort2v v[8];
#pragma unroll
        for (int u = 0; u < 8; ++u)
            v[u] = *reinterpret_cast<const ushort2v*>(hcbr + (size_t)s[u] * 20 + c0);
#pragma unroll
        for (int u = 0; u < 8; ++u) {
            float x0 = bf2f(v[u][0]), x1 = bf2f(v[u][1]);
            dd0[0] += d0[u] * x0;  dd0[1] += d0[u] * x1;
            dd1[0] += d1[u] * x0;  dd1[1] += d1[u] * x1;
            da0[0] += a0w[u] * x0; da0[1] += a0w[u] * x1;
            da1[0] += a1w[u] * x0; da1[1] += a1w[u] * x1;
        }
    }
    for (; e < e1; ++e) {
        int s = src[e];
        float d0 = kdd[e], d1 = kdd[N_EDGES + e];
        float a0w = kda[e], a1w = kda[N_EDGES + e];
        ushort2v v = *reinterpret_cast<const ushort2v*>(hcbr + (size_t)s * 20 + c0);
        float x0 = bf2f(v[0]), x1 = bf2f(v[1]);
        dd0[0] += d0 * x0;  dd0[1] += d0 * x1;
        dd1[0] += d1 * x0;  dd1[1] += d1 * x1;
        da0[0] += a0w * x0; da0[1] += a0w * x1;
        da1[0] += a1w * x0; da1[1] += a1w * x1;
    }

    ushort2v w;
    w[0] = f2bf(dd0[0]); w[1] = f2bf(dd0[1]);
    *reinterpret_cast<ushort2v*>(hcbw + (size_t)t * 20 + 6 + c0) = w;
    w[0] = f2bf(dd1[0]); w[1] = f2bf(dd1[1]);
    *reinterpret_cast<ushort2v*>(hcbw + (size_t)t * 20 + 12 + c0) = w;
    w[0] = f2bf(da0[0]); w[1] = f2bf(da0[1]);
    *reinterpret_cast<ushort2v*>(h3b + (size_t)t * 64 + c0) = w;
    w[0] = f2bf(da1[0]); w[1] = f2bf(da1[1]);
    *reinterpret_cast<ushort2v*>(h3b + (size_t)t * 64 + 18 + c0) = w;
}

// ---------------- conv3b: gather h2 (hcb cols 6:18), kda -> h3 cols --------
// Thread (t,g), g<6, h2 channels m=2g..2g+1 -> h3 cols {6+m, 24+m}.
__global__ __launch_bounds__(256) void conv3b_k(const unsigned short* __restrict__ hcb,
                                                const float* __restrict__ kda,
                                                const int* __restrict__ src,
                                                const int* __restrict__ rp,
                                                unsigned short* __restrict__ h3b) {
    int id = blockIdx.x * blockDim.x + threadIdx.x;
    if (id >= N_NODES * 6) return;
    int t = id / 6;
    int g = id - t * 6;
    int c0 = g * 2;
    int e0 = rp[t], e1 = rp[t + 1];

    float da0[2] = {0.f, 0.f}, da1[2] = {0.f, 0.f};

    int e = e0;
    for (; e + 8 <= e1; e += 8) {
        int s[8]; float a0w[8], a1w[8];
#pragma unroll
        for (int u = 0; u < 8; ++u) s[u]   = src[e + u];
#pragma unroll
        for (int u = 0; u < 8; ++u) a0w[u] = kda[e + u];
#pragma unroll
        for (int u = 0; u < 8; ++u) a1w[u] = kda[N_EDGES + e + u];
        ushort2v v[8];
#pragma unroll
        for (int u = 0; u < 8; ++u)
            v[u] = *reinterpret_cast<const ushort2v*>(hcb + (size_t)s[u] * 20 + 6 + c0);
#pragma unroll
        for (int u = 0; u < 8; ++u) {
            float x0 = bf2f(v[u][0]), x1 = bf2f(v[u][1]);
            da0[0] += a0w[u] * x0; da0[1] += a0w[u] * x1;
            da1[0] += a1w[u] * x0; da1[1] += a1w[u] * x1;
        }
    }
    for (; e < e1; ++e) {
        int s = src[e];
        float a0w = kda[e], a1w = kda[N_EDGES + e];
        ushort2v v = *reinterpret_cast<const ushort2v*>(hcb + (size_t)s * 20 + 6 + c0);
        float x0 = bf2f(v[0]), x1 = bf2f(v[1]);
        da0[0] += a0w * x0; da0[1] += a0w * x1;
        da1[0] += a1w * x0; da1[1] += a1w * x1;
    }

    ushort2v w;
    w[0] = f2bf(da0[0]); w[1] = f2bf(da0[1]);
    *reinterpret_cast<ushort2v*>(h3b + (size_t)t * 64 + 6 + c0) = w;
    w[0] = f2bf(da1[0]); w[1] = f2bf(da1[1]);
    *reinterpret_cast<ushort2v*>(h3b + (size_t)t * 64 + 24 + c0) = w;

    if (g == 5) {   // zero K-pad cols 36..63
        ushort4v z = {0, 0, 0, 0};
#pragma unroll
        for (int j = 36; j < 64; j += 4)
            *reinterpret_cast<ushort4v*>(h3b + (size_t)t * 64 + j) = z;
    }
}

template<int VEC> struct VecU;
template<> struct VecU<4> { using T = ushort4v; };
template<> struct VecU<8> { using T = ushort8v; };

// ---------------- bf16 aniso conv (conv4) ----------------------------------
template<int C, int VEC, int IN_STRIDE, int OUT_STRIDE, int OUT_OFF,
         int PAD_FROM, int PAD_TO>
__global__ __launch_bounds__(256) void convb_k(const unsigned short* __restrict__ hin,
                                               const float* __restrict__ kv,
                                               const int* __restrict__ src,
                                               const int* __restrict__ rp,
                                               unsigned short* __restrict__ hout) {
    constexpr int G = C / VEC;
    using VT = typename VecU<VEC>::T;
    int id = blockIdx.x * blockDim.x + threadIdx.x;
    if (id >= N_NODES * G) return;
    int t = id / G;
    int g = id - t * G;
    int c0 = g * VEC;
    int e0 = rp[t], e1 = rp[t + 1];

    float a0[VEC], a1[VEC];
#pragma unroll
    for (int q = 0; q < VEC; ++q) { a0[q] = 0.f; a1[q] = 0.f; }

    int e = e0;
    for (; e + 8 <= e1; e += 8) {
        int s[8]; float k0[8], k1[8];
#pragma unroll
        for (int u = 0; u < 8; ++u) s[u]  = src[e + u];
#pragma unroll
        for (int u = 0; u < 8; ++u) k0[u] = kv[e + u];
#pragma unroll
        for (int u = 0; u < 8; ++u) k1[u] = kv[N_EDGES + e + u];
        VT v[8];
#pragma unroll
        for (int u = 0; u < 8; ++u)
            v[u] = *reinterpret_cast<const VT*>(hin + (size_t)s[u] * IN_STRIDE + c0);
#pragma unroll
        for (int u = 0; u < 8; ++u) {
#pragma unroll
            for (int q = 0; q < VEC; ++q) {
                float x = bf2f(v[u][q]);
                a0[q] += k0[u] * x;
                a1[q] += k1[u] * x;
            }
        }
    }
    for (; e < e1; ++e) {
        int s = src[e];
        float k0 = kv[e], k1 = kv[N_EDGES + e];
        VT v = *reinterpret_cast<const VT*>(hin + (size_t)s * IN_STRIDE + c0);
#pragma unroll
        for (int q = 0; q < VEC; ++q) {
            float x = bf2f(v[q]);
            a0[q] += k0 * x;
            a1[q] += k1 * x;
        }
    }

    VT r0, r1;
#pragma unroll
    for (int q = 0; q < VEC; ++q) { r0[q] = f2bf(a0[q]); r1[q] = f2bf(a1[q]); }
    *reinterpret_cast<VT*>(hout + (size_t)t * OUT_STRIDE + OUT_OFF + c0)     = r0;
    *reinterpret_cast<VT*>(hout + (size_t)t * OUT_STRIDE + OUT_OFF + C + c0) = r1;

    if constexpr (PAD_TO > PAD_FROM) {
        if (g == G - 1) {
            ushort4v z = {0, 0, 0, 0};
#pragma unroll
            for (int j = PAD_FROM; j < PAD_TO; j += 4)
                *reinterpret_cast<ushort4v*>(hout + (size_t)t * OUT_STRIDE + j) = z;
        }
    }
}

// ---------------- lin0 via MFMA: h4b = relu(h3b[N][64] @ w0t + b0) ---------
__global__ __launch_bounds__(256) void lin0m_k(const unsigned short* __restrict__ h3b,
                                               const unsigned short* __restrict__ w0t,
                                               const float* __restrict__ b0,
                                               unsigned short* __restrict__ h4b) {
    int tid = threadIdx.x;
    int w = tid >> 6;
    int lane = tid & 63;
    int lr = lane & 15;
    int kg = lane >> 4;
    int row_base = blockIdx.x * 64 + w * 16;

    f32x4 acc[5];
#pragma unroll
    for (int n = 0; n < 5; ++n) acc[n] = (f32x4){0.f, 0.f, 0.f, 0.f};

    const unsigned short* arow = h3b + (size_t)(row_base + lr) * 64 + kg * 8;
#pragma unroll
    for (int ks = 0; ks < 2; ++ks) {
        short8 a = *reinterpret_cast<const short8*>(arow + ks * 32);
#pragma unroll
        for (int n = 0; n < 5; ++n) {
            short8 b = *reinterpret_cast<const short8*>(w0t + (n * 16 + lr) * 64 + ks * 32 + kg * 8);
            acc[n] = __builtin_amdgcn_mfma_f32_16x16x32_bf16(a, b, acc[n], 0, 0, 0);
        }
    }
#pragma unroll
    for (int n = 0; n < 5; ++n) {
        int col = n * 16 + lr;
        if (col < 72) {
            float bv = b0[col];
#pragma unroll
            for (int q = 0; q < 4; ++q) {
                int t = row_base + kg * 4 + q;
                if (t < N_NODES)
                    h4b[(size_t)t * 72 + col] = f2bf(fmaxf(acc[n][q] + bv, 0.f));
            }
        }
    }
}

// ---------------- MFMA MLP head + L2 normalize -----------------------------
#define HSTRIDE 136
__global__ __launch_bounds__(256) void mlp_k(const unsigned short* __restrict__ h5b,
                                             const unsigned short* __restrict__ w1t,
                                             const float* __restrict__ b1,
                                             const unsigned short* __restrict__ w2t,
                                             const float* __restrict__ b2,
                                             float* __restrict__ out) {
    __shared__ unsigned short sh[64 * HSTRIDE];
    int tid = threadIdx.x;
    int w = tid >> 6;
    int lane = tid & 63;
    int lr = lane & 15;
    int kg = lane >> 4;
    int row_base = blockIdx.x * 64 + w * 16;

    f32x4 acc[8];
#pragma unroll
    for (int n = 0; n < 8; ++n) acc[n] = (f32x4){0.f, 0.f, 0.f, 0.f};

    const unsigned short* arow = h5b + (size_t)(row_base + lr) * 160 + kg * 8;
#pragma unroll
    for (int ks = 0; ks < 5; ++ks) {
        short8 a = *reinterpret_cast<const short8*>(arow + ks * 32);
#pragma unroll
        for (int n = 0; n < 8; ++n) {
            short8 b = *reinterpret_cast<const short8*>(w1t + (n * 16 + lr) * 160 + ks * 32 + kg * 8);
            acc[n] = __builtin_amdgcn_mfma_f32_16x16x32_bf16(a, b, acc[n], 0, 0, 0);
        }
    }
#pragma unroll
    for (int n = 0; n < 8; ++n) {
        float bv = b1[n * 16 + lr];
#pragma unroll
        for (int q = 0; q < 4; ++q) {
            float hv = fmaxf(acc[n][q] + bv, 0.f);
            sh[(w * 16 + kg * 4 + q) * HSTRIDE + n * 16 + lr] = f2bf(hv);
        }
    }
    __syncthreads();

    f32x4 acc2[4];
#pragma unroll
    for (int n = 0; n < 4; ++n) acc2[n] = (f32x4){0.f, 0.f, 0.f, 0.f};
#pragma unroll
    for (int ks = 0; ks < 4; ++ks) {
        short8 a = *reinterpret_cast<const short8*>(sh + (w * 16 + lr) * HSTRIDE + ks * 32 + kg * 8);
#pragma unroll
        for (int n = 0; n < 4; ++n) {
            short8 b = *reinterpret_cast<const short8*>(w2t + (n * 16 + lr) * 128 + ks * 32 + kg * 8);
            acc2[n] = __builtin_amdgcn_mfma_f32_16x16x32_bf16(a, b, acc2[n], 0, 0, 0);
        }
    }

    float v[4][4];
    float ss[4];
#pragma unroll
    for (int q = 0; q < 4; ++q) ss[q] = 0.f;
#pragma unroll
    for (int n = 0; n < 4; ++n) {
        float bv = b2[n * 16 + lr];
#pragma unroll
        for (int q = 0; q < 4; ++q) {
            float x = acc2[n][q] + bv;
            v[n][q] = x;
            ss[q] += x * x;
        }
    }
#pragma unroll
    for (int q = 0; q < 4; ++q) {
#pragma unroll
        for (int d = 1; d < 16; d <<= 1) ss[q] += __shfl_xor(ss[q], d);
    }
#pragma unroll
    for (int q = 0; q < 4; ++q) {
        int node = row_base + kg * 4 + q;
        if (node < N_NODES) {
            float scale = 1.f / fmaxf(sqrtf(ss[q]), 1e-12f);
#pragma unroll
            for (int n = 0; n < 4; ++n)
                out[(size_t)node * 64 + n * 16 + lr] = v[n][q] * scale;
        }
    }
}

extern "C" void kernel_launch(void* const* d_in, const int* in_sizes, int n_in,
                              void* d_out, int out_size, void* d_ws, size_t ws_size,
                              hipStream_t stream) {
    const float* x   = (const float*)d_in[0];
    const float* kdd = (const float*)d_in[1];
    const float* kda = (const float*)d_in[2];
    const float* l0w = (const float*)d_in[3];
    const float* l0b = (const float*)d_in[4];
    const float* w1  = (const float*)d_in[5];
    const float* b1  = (const float*)d_in[6];
    const float* w2  = (const float*)d_in[7];
    const float* b2  = (const float*)d_in[8];
    const int*   src = (const int*)d_in[9];
    const int*   dst = (const int*)d_in[10];
    float* out = (float*)d_out;
    char* ws = (char*)d_ws;

    // workspace layout (bytes):
    //   rp    [0, +400004)
    //   w0t   [400384, +10240)        bf16 80x64
    //   w1t   [410624, +40960)        bf16 128x160
    //   w2t   [451584, +16384)        bf16 64x128
    //   hcb   [475136, +4.0 MB)       bf16 N*20   (h1 cols 0:6, h2 cols 6:18)
    //   h3b   [4480000, +12.80 MB)    bf16 100032*64 (K-padded)
    //   h4b   [17284096, +14.4 MB)    bf16 N*72
    //   h5b   [31684096, +32.01 MB)   bf16 100032*160
    int*   rp  = (int*)ws;
    unsigned short* w0t = (unsigned short*)(ws + 400384u);
    unsigned short* w1t = (unsigned short*)(ws + 410624u);
    unsigned short* w2t = (unsigned short*)(ws + 451584u);
    unsigned short* hcb = (unsigned short*)(ws + 475136u);
    unsigned short* h3b = (unsigned short*)(ws + 4480000u);
    unsigned short* h4b = (unsigned short*)(ws + 17284096u);
    unsigned short* h5b = (unsigned short*)(ws + 31684096u);

    rowptr_k<<<(N_NODES + 1 + 255) / 256, 256, 0, stream>>>(dst, rp);
    prep_k<<<(128 * 160 + 64 * 128 + 80 * 64 + 255) / 256, 256, 0, stream>>>(w1, w2, l0w, w1t, w2t, w0t);

    // DD phase + DA-h1 part: conv1 -> fused conv2+conv3a -> conv3b
    conv1_k<<<(N_NODES * 3 + 255) / 256, 256, 0, stream>>>(x, kdd, src, rp, hcb);
    f23a_k<<<(N_NODES * 3 + 255) / 256, 256, 0, stream>>>(hcb, kdd, kda, src, rp, hcb, h3b);
    conv3b_k<<<(N_NODES * 6 + 255) / 256, 256, 0, stream>>>(hcb, kda, src, rp, h3b);

    // DA tail
    lin0m_k<<<(N_NODES + 63) / 64, 256, 0, stream>>>(h3b, w0t, l0b, h4b);
    convb_k<72, 8, 72, 160, 0, 144, 160><<<(N_NODES * 9 + 255) / 256, 256, 0, stream>>>(h4b, kda, src, rp, h5b);

    // MFMA MLP head + normalize
    mlp_k<<<(N_NODES + 63) / 64, 256, 0, stream>>>(h5b, w1t, b1, w2t, b2, out);
}